// Round 3
// baseline (855.734 us; speedup 1.0000x reference)
//
#include <hip/hip_runtime.h>
#include <math.h>

#define N_NODES 650
#define DIM     512
#define E_RAW   150000
#define E_TOT   150650

#define BM 32
#define BN 64
#define BK 32
#define RPB 16   // dst rows per block in edge kernel

// =============== h-GEMM: C[M,N] = Aload @ B, fused logits ===============
// a_mode 0: A plain [M,K]
// a_mode 1: rows <400 from A (x_s), rows >=400 from Axt (x_t)
// Epilogue also accumulates als[r] += sum_c C[r,c]*asrc[c], same for ald.
__global__ __launch_bounds__(256)
void gemm_h(const float* __restrict__ A, const float* __restrict__ Axt,
            const float* __restrict__ B,
            const float* __restrict__ asrc, const float* __restrict__ adst,
            float* __restrict__ C, float* __restrict__ als, float* __restrict__ ald,
            int M, int N, int K, int a_mode) {
    __shared__ float Ast[BK][BM + 2];   // [kk][m], pad->stride 34 (8B aligned)
    __shared__ float Bs[BK][BN];
    int t  = threadIdx.x;
    int tx = t & 15, ty = t >> 4;
    int row0 = blockIdx.y * BM, col0 = blockIdx.x * BN;
    float acc[2][4] = {};

    for (int kb = 0; kb < K; kb += BK) {
        for (int l = t; l < BM * BK; l += 256) {
            int m = l >> 5, kk = l & 31;
            int gr = row0 + m, gk = kb + kk;
            float v = 0.f;
            if (gr < M && gk < K) {
                if (a_mode == 1)
                    v = (gr < 400) ? A[gr * DIM + gk] : Axt[(gr - 400) * DIM + gk];
                else
                    v = A[gr * K + gk];
            }
            Ast[kk][m] = v;
        }
        for (int l = t; l < BK * BN; l += 256) {
            int kk = l >> 6, n = l & 63;
            int gk = kb + kk;
            Bs[kk][n] = (gk < K) ? B[gk * N + col0 + n] : 0.f;
        }
        __syncthreads();
        #pragma unroll
        for (int kk = 0; kk < BK; kk++) {
            float2 a2 = *(const float2*)&Ast[kk][ty * 2];
            float4 b4 = *(const float4*)&Bs[kk][tx * 4];
            acc[0][0] += a2.x * b4.x; acc[0][1] += a2.x * b4.y;
            acc[0][2] += a2.x * b4.z; acc[0][3] += a2.x * b4.w;
            acc[1][0] += a2.y * b4.x; acc[1][1] += a2.y * b4.y;
            acc[1][2] += a2.y * b4.z; acc[1][3] += a2.y * b4.w;
        }
        __syncthreads();
    }

    int gc0 = col0 + tx * 4;
    float as0 = asrc[gc0 + 0], as1 = asrc[gc0 + 1], as2 = asrc[gc0 + 2], as3 = asrc[gc0 + 3];
    float ad0 = adst[gc0 + 0], ad1 = adst[gc0 + 1], ad2 = adst[gc0 + 2], ad3 = adst[gc0 + 3];
    #pragma unroll
    for (int i = 0; i < 2; i++) {
        int gr = row0 + ty * 2 + i;
        if (gr >= M) continue;
        *(float4*)&C[gr * N + gc0] = make_float4(acc[i][0], acc[i][1], acc[i][2], acc[i][3]);
        float ps = acc[i][0] * as0 + acc[i][1] * as1 + acc[i][2] * as2 + acc[i][3] * as3;
        float pd = acc[i][0] * ad0 + acc[i][1] * ad1 + acc[i][2] * ad2 + acc[i][3] * ad3;
        #pragma unroll
        for (int o = 8; o > 0; o >>= 1) {
            ps += __shfl_down(ps, o);
            pd += __shfl_down(pd, o);
        }
        if (tx == 0) {
            atomicAdd(&als[gr], ps);
            atomicAdd(&ald[gr], pd);
        }
    }
}

// =============== agg-GEMM: C = act( (Aalpha @ h)/srow + bias ) ===============
// act: 1 = relu, 2 = leaky_relu(0.01)
__global__ __launch_bounds__(256)
void gemm_agg(const float* __restrict__ A, const float* __restrict__ B,
              const float* __restrict__ srow, const float* __restrict__ bias,
              float* __restrict__ C, int M, int N, int K, int act) {
    __shared__ float Ast[BK][BM + 2];
    __shared__ float Bs[BK][BN];
    int t  = threadIdx.x;
    int tx = t & 15, ty = t >> 4;
    int row0 = blockIdx.y * BM, col0 = blockIdx.x * BN;
    float acc[2][4] = {};

    for (int kb = 0; kb < K; kb += BK) {
        for (int l = t; l < BM * BK; l += 256) {
            int m = l >> 5, kk = l & 31;
            int gr = row0 + m, gk = kb + kk;
            Ast[kk][m] = (gr < M && gk < K) ? A[gr * K + gk] : 0.f;
        }
        for (int l = t; l < BK * BN; l += 256) {
            int kk = l >> 6, n = l & 63;
            int gk = kb + kk;
            Bs[kk][n] = (gk < K) ? B[gk * N + col0 + n] : 0.f;
        }
        __syncthreads();
        #pragma unroll
        for (int kk = 0; kk < BK; kk++) {
            float2 a2 = *(const float2*)&Ast[kk][ty * 2];
            float4 b4 = *(const float4*)&Bs[kk][tx * 4];
            acc[0][0] += a2.x * b4.x; acc[0][1] += a2.x * b4.y;
            acc[0][2] += a2.x * b4.z; acc[0][3] += a2.x * b4.w;
            acc[1][0] += a2.y * b4.x; acc[1][1] += a2.y * b4.y;
            acc[1][2] += a2.y * b4.z; acc[1][3] += a2.y * b4.w;
        }
        __syncthreads();
    }

    int gc0 = col0 + tx * 4;
    float b0 = bias[gc0 + 0], b1 = bias[gc0 + 1], b2 = bias[gc0 + 2], b3 = bias[gc0 + 3];
    #pragma unroll
    for (int i = 0; i < 2; i++) {
        int gr = row0 + ty * 2 + i;
        if (gr >= M) continue;
        float inv = 1.f / (srow[gr] + 1e-16f);
        float v0 = acc[i][0] * inv + b0;
        float v1 = acc[i][1] * inv + b1;
        float v2 = acc[i][2] * inv + b2;
        float v3 = acc[i][3] * inv + b3;
        float slope = (act == 1) ? 0.f : 0.01f;
        v0 = v0 > 0.f ? v0 : slope * v0;
        v1 = v1 > 0.f ? v1 : slope * v1;
        v2 = v2 > 0.f ? v2 : slope * v2;
        v3 = v3 > 0.f ? v3 : slope * v3;
        *(float4*)&C[gr * N + gc0] = make_float4(v0, v1, v2, v3);
    }
}

// ========== edge pass: dst-partitioned, LDS accumulation, plain stores ==========
// Block b owns dst rows [b*RPB, b*RPB+RPB). Writes Aout rows + sout (unnormalized).
__global__ __launch_bounds__(256)
void edge_build(const int* __restrict__ ei,
                const float* __restrict__ als, const float* __restrict__ ald,
                float* __restrict__ Aout, float* __restrict__ sout) {
    __shared__ float Ar[RPB * N_NODES];
    __shared__ float ss[RPB];
    int t = threadIdx.x;
    int base = blockIdx.x * RPB;
    for (int l = t; l < RPB * N_NODES; l += 256) Ar[l] = 0.f;
    if (t < RPB) ss[t] = 0.f;
    __syncthreads();

    for (int i = t; i < E_TOT; i += 256) {
        int s, d;
        if (i < E_RAW) { s = ei[i]; d = ei[E_RAW + i]; }
        else           { s = d = i - E_RAW; }
        int ld = d - base;
        if ((unsigned)ld < RPB) {
            float v = als[s] + ald[d];
            v = v > 0.f ? v : 0.2f * v;
            float ex = __expf(v);
            atomicAdd(&Ar[ld * N_NODES + s], ex);
            atomicAdd(&ss[ld], ex);
        }
    }
    __syncthreads();

    for (int l = t; l < RPB * N_NODES; l += 256) {
        int r = base + l / N_NODES;
        if (r < N_NODES) Aout[r * N_NODES + (l % N_NODES)] = Ar[l];
    }
    if (t < RPB && base + t < N_NODES) sout[base + t] = ss[t];
}

// ========== final: reshape(512,650) @ fc_w + fc_b -> sigmoid ==========
__global__ void final_kernel(const float* __restrict__ o2,
                             const float* __restrict__ fcw,
                             const float* __restrict__ fcb,
                             float* __restrict__ out) {
    int b = blockIdx.x * 4 + (threadIdx.x >> 6);
    int lane = threadIdx.x & 63;
    if (b >= 512) return;
    float s = 0.f;
    for (int i = lane; i < N_NODES; i += 64)
        s += o2[b * N_NODES + i] * fcw[i];
    #pragma unroll
    for (int o = 32; o > 0; o >>= 1) s += __shfl_down(s, o);
    if (lane == 0) out[b] = 1.f / (1.f + expf(-(s + fcb[0])));
}

extern "C" void kernel_launch(void* const* d_in, const int* in_sizes, int n_in,
                              void* d_out, int out_size, void* d_ws, size_t ws_size,
                              hipStream_t stream) {
    const float* x_s   = (const float*)d_in[0];
    const float* x_t   = (const float*)d_in[1];
    const int*   ei    = (const int*)d_in[2];
    const float* W1    = (const float*)d_in[5];
    const float* asrc1 = (const float*)d_in[6];
    const float* adst1 = (const float*)d_in[7];
    const float* b1    = (const float*)d_in[8];
    const float* W4    = (const float*)d_in[9];
    const float* asrc4 = (const float*)d_in[10];
    const float* adst4 = (const float*)d_in[11];
    const float* b4    = (const float*)d_in[12];
    const float* fcw   = (const float*)d_in[13];
    const float* fcb   = (const float*)d_in[14];
    float* out = (float*)d_out;

    float* ws = (float*)d_ws;
    const size_t A_ELEMS = (size_t)N_NODES * N_NODES;   // 422500
    const size_t H_ELEMS = (size_t)N_NODES * DIM;       // 332800
    float* A1   = ws;
    float* A2   = A1 + A_ELEMS;
    float* h1   = A2 + A_ELEMS;
    float* h2   = h1 + H_ELEMS;
    float* o1   = h2 + H_ELEMS;
    float* o2   = o1 + H_ELEMS;
    float* s1   = o2 + H_ELEMS;
    float* s2   = s1 + N_NODES;
    float* als1 = s2 + N_NODES;      // zeroed region: als1,ald1,als2,ald2
    float* ald1 = als1 + N_NODES;
    float* als2 = ald1 + N_NODES;
    float* ald2 = als2 + N_NODES;

    hipMemsetAsync(als1, 0, 4 * N_NODES * sizeof(float), stream);

    dim3 gG(DIM / BN, (N_NODES + BM - 1) / BM);         // 8 x 21
    int nbE = (N_NODES + RPB - 1) / RPB;                // 41

    // ---- layer 1 ----
    gemm_h<<<gG, 256, 0, stream>>>(x_s, x_t, W1, asrc1, adst1,
                                   h1, als1, ald1, N_NODES, DIM, DIM, 1);
    edge_build<<<nbE, 256, 0, stream>>>(ei, als1, ald1, A1, s1);
    gemm_agg<<<gG, 256, 0, stream>>>(A1, h1, s1, b1, o1,
                                     N_NODES, DIM, N_NODES, 1);

    // ---- layer 2 ----
    gemm_h<<<gG, 256, 0, stream>>>(o1, nullptr, W4, asrc4, adst4,
                                   h2, als2, ald2, N_NODES, DIM, DIM, 0);
    edge_build<<<nbE, 256, 0, stream>>>(ei, als2, ald2, A2, s2);
    gemm_agg<<<gG, 256, 0, stream>>>(A2, h2, s2, b4, o2,
                                     N_NODES, DIM, N_NODES, 2);

    // ---- final ----
    final_kernel<<<128, 256, 0, stream>>>(o2, fcw, fcb, out);
}

// Round 4
// 308.638 us; speedup vs baseline: 2.7726x; 2.7726x over previous
//
#include <hip/hip_runtime.h>
#include <math.h>

#define N_NODES 650
#define DIM     512
#define E_RAW   150000
#define E_TOT   150650

#define BM 32
#define BN 64
#define BK 32
#define CH 1024   // SpMM edge chunk (LDS)

// =============== h-GEMM: C[M,N] = Aload @ B, fused logits ===============
__global__ __launch_bounds__(256)
void gemm_h(const float* __restrict__ A, const float* __restrict__ Axt,
            const float* __restrict__ B,
            const float* __restrict__ asrc, const float* __restrict__ adst,
            float* __restrict__ C, float* __restrict__ als, float* __restrict__ ald,
            int M, int N, int K, int a_mode) {
    __shared__ float Ast[BK][BM + 2];
    __shared__ float Bs[BK][BN];
    int t  = threadIdx.x;
    int tx = t & 15, ty = t >> 4;
    int row0 = blockIdx.y * BM, col0 = blockIdx.x * BN;
    float acc[2][4] = {};

    for (int kb = 0; kb < K; kb += BK) {
        for (int l = t; l < BM * BK; l += 256) {
            int m = l >> 5, kk = l & 31;
            int gr = row0 + m, gk = kb + kk;
            float v = 0.f;
            if (gr < M && gk < K) {
                if (a_mode == 1)
                    v = (gr < 400) ? A[gr * DIM + gk] : Axt[(gr - 400) * DIM + gk];
                else
                    v = A[gr * K + gk];
            }
            Ast[kk][m] = v;
        }
        for (int l = t; l < BK * BN; l += 256) {
            int kk = l >> 6, n = l & 63;
            int gk = kb + kk;
            Bs[kk][n] = (gk < K) ? B[gk * N + col0 + n] : 0.f;
        }
        __syncthreads();
        #pragma unroll
        for (int kk = 0; kk < BK; kk++) {
            float2 a2 = *(const float2*)&Ast[kk][ty * 2];
            float4 b4 = *(const float4*)&Bs[kk][tx * 4];
            acc[0][0] += a2.x * b4.x; acc[0][1] += a2.x * b4.y;
            acc[0][2] += a2.x * b4.z; acc[0][3] += a2.x * b4.w;
            acc[1][0] += a2.y * b4.x; acc[1][1] += a2.y * b4.y;
            acc[1][2] += a2.y * b4.z; acc[1][3] += a2.y * b4.w;
        }
        __syncthreads();
    }

    int gc0 = col0 + tx * 4;
    float as0 = asrc[gc0 + 0], as1 = asrc[gc0 + 1], as2 = asrc[gc0 + 2], as3 = asrc[gc0 + 3];
    float ad0 = adst[gc0 + 0], ad1 = adst[gc0 + 1], ad2 = adst[gc0 + 2], ad3 = adst[gc0 + 3];
    #pragma unroll
    for (int i = 0; i < 2; i++) {
        int gr = row0 + ty * 2 + i;
        if (gr >= M) continue;
        *(float4*)&C[gr * N + gc0] = make_float4(acc[i][0], acc[i][1], acc[i][2], acc[i][3]);
        float ps = acc[i][0] * as0 + acc[i][1] * as1 + acc[i][2] * as2 + acc[i][3] * as3;
        float pd = acc[i][0] * ad0 + acc[i][1] * ad1 + acc[i][2] * ad2 + acc[i][3] * ad3;
        #pragma unroll
        for (int o = 8; o > 0; o >>= 1) {
            ps += __shfl_down(ps, o);
            pd += __shfl_down(pd, o);
        }
        if (tx == 0) {
            atomicAdd(&als[gr], ps);
            atomicAdd(&ald[gr], pd);
        }
    }
}

// =============== CSR build pass 1: per-dst histogram ===============
__global__ __launch_bounds__(256)
void hist_kernel(const int* __restrict__ ei, int* __restrict__ cnt) {
    __shared__ int h[N_NODES];
    for (int l = threadIdx.x; l < N_NODES; l += 256) h[l] = 0;
    __syncthreads();
    for (int i = blockIdx.x * 256 + threadIdx.x; i < E_TOT; i += gridDim.x * 256) {
        int d = (i < E_RAW) ? ei[E_RAW + i] : i - E_RAW;
        atomicAdd(&h[d], 1);
    }
    __syncthreads();
    for (int l = threadIdx.x; l < N_NODES; l += 256) {
        int v = h[l];
        if (v) atomicAdd(&cnt[l], v);
    }
}

// =============== CSR build pass 2: exclusive prefix (1 block, 1024 thr) ===============
__global__ __launch_bounds__(1024)
void scan_kernel(const int* __restrict__ cnt, int* __restrict__ rowptr,
                 int* __restrict__ cursor) {
    __shared__ int buf[1024];
    int t = threadIdx.x;
    buf[t] = (t < N_NODES) ? cnt[t] : 0;
    __syncthreads();
    #pragma unroll
    for (int o = 1; o < 1024; o <<= 1) {
        int v = (t >= o) ? buf[t - o] : 0;
        __syncthreads();
        buf[t] += v;
        __syncthreads();
    }
    if (t < N_NODES) {
        int excl = (t == 0) ? 0 : buf[t - 1];
        rowptr[t] = excl;
        cursor[t] = excl;
    }
    if (t == 0) rowptr[N_NODES] = buf[N_NODES - 1];
}

// =============== CSR build pass 3: scatter srcs into dst-sorted order ===============
__global__ __launch_bounds__(256)
void scatter_kernel(const int* __restrict__ ei, int* __restrict__ cursor,
                    int* __restrict__ ssrc) {
    int i = blockIdx.x * 256 + threadIdx.x;
    if (i >= E_TOT) return;
    int s, d;
    if (i < E_RAW) { s = ei[i]; d = ei[E_RAW + i]; }
    else           { s = d = i - E_RAW; }
    int pos = atomicAdd(&cursor[d], 1);
    ssrc[pos] = s;
}

// =============== SpMM: out[d] = act( (Σ_e ex_e·h[src_e]) / Σ ex + bias ) ===============
// block = dst node; 256 threads, thread t owns dims t and t+256.
__global__ __launch_bounds__(256)
void spmm_kernel(const int* __restrict__ rowptr, const int* __restrict__ ssrc,
                 const float* __restrict__ als, const float* __restrict__ ald,
                 const float* __restrict__ h, const float* __restrict__ bias,
                 float slope, float* __restrict__ outm) {
    __shared__ int   sS[CH];
    __shared__ float sE[CH];
    __shared__ float red[4];
    int d = blockIdx.x;
    int t = threadIdx.x;
    int r0 = rowptr[d], r1 = rowptr[d + 1];
    int deg = r1 - r0;
    float aldd = ald[d];
    float acc0 = 0.f, acc1 = 0.f, psum = 0.f;

    for (int cb = 0; cb < deg; cb += CH) {
        int n = min(CH, deg - cb);
        __syncthreads();
        for (int l = t; l < n; l += 256) {
            int s = ssrc[r0 + cb + l];
            float v = als[s] + aldd;
            v = v > 0.f ? v : 0.2f * v;
            float ex = __expf(v);
            sS[l] = s;
            sE[l] = ex;
            psum += ex;
        }
        __syncthreads();
        int e = 0;
        for (; e + 4 <= n; e += 4) {
            int   s0 = sS[e],   s1 = sS[e+1], s2 = sS[e+2], s3 = sS[e+3];
            float e0 = sE[e],   e1 = sE[e+1], e2 = sE[e+2], e3 = sE[e+3];
            const float* p0 = &h[s0 * DIM];
            const float* p1 = &h[s1 * DIM];
            const float* p2 = &h[s2 * DIM];
            const float* p3 = &h[s3 * DIM];
            float x00 = p0[t], x01 = p0[t + 256];
            float x10 = p1[t], x11 = p1[t + 256];
            float x20 = p2[t], x21 = p2[t + 256];
            float x30 = p3[t], x31 = p3[t + 256];
            acc0 += e0 * x00; acc1 += e0 * x01;
            acc0 += e1 * x10; acc1 += e1 * x11;
            acc0 += e2 * x20; acc1 += e2 * x21;
            acc0 += e3 * x30; acc1 += e3 * x31;
        }
        for (; e < n; e++) {
            int s = sS[e]; float ex = sE[e];
            acc0 += ex * h[s * DIM + t];
            acc1 += ex * h[s * DIM + t + 256];
        }
    }

    #pragma unroll
    for (int o = 32; o > 0; o >>= 1) psum += __shfl_down(psum, o);
    if ((t & 63) == 0) red[t >> 6] = psum;
    __syncthreads();
    float sum = red[0] + red[1] + red[2] + red[3];
    float inv = 1.f / (sum + 1e-16f);
    float v0 = acc0 * inv + bias[t];
    float v1 = acc1 * inv + bias[t + 256];
    v0 = v0 > 0.f ? v0 : slope * v0;
    v1 = v1 > 0.f ? v1 : slope * v1;
    outm[d * DIM + t]       = v0;
    outm[d * DIM + t + 256] = v1;
}

// =============== final: reshape(512,650) @ fc_w + fc_b -> sigmoid ===============
__global__ void final_kernel(const float* __restrict__ o2,
                             const float* __restrict__ fcw,
                             const float* __restrict__ fcb,
                             float* __restrict__ out) {
    int b = blockIdx.x * 4 + (threadIdx.x >> 6);
    int lane = threadIdx.x & 63;
    if (b >= 512) return;
    float s = 0.f;
    for (int i = lane; i < N_NODES; i += 64)
        s += o2[b * N_NODES + i] * fcw[i];
    #pragma unroll
    for (int o = 32; o > 0; o >>= 1) s += __shfl_down(s, o);
    if (lane == 0) out[b] = 1.f / (1.f + expf(-(s + fcb[0])));
}

extern "C" void kernel_launch(void* const* d_in, const int* in_sizes, int n_in,
                              void* d_out, int out_size, void* d_ws, size_t ws_size,
                              hipStream_t stream) {
    const float* x_s   = (const float*)d_in[0];
    const float* x_t   = (const float*)d_in[1];
    const int*   ei    = (const int*)d_in[2];
    const float* W1    = (const float*)d_in[5];
    const float* asrc1 = (const float*)d_in[6];
    const float* adst1 = (const float*)d_in[7];
    const float* b1    = (const float*)d_in[8];
    const float* W4    = (const float*)d_in[9];
    const float* asrc4 = (const float*)d_in[10];
    const float* adst4 = (const float*)d_in[11];
    const float* b4    = (const float*)d_in[12];
    const float* fcw   = (const float*)d_in[13];
    const float* fcb   = (const float*)d_in[14];
    float* out = (float*)d_out;

    const size_t H_ELEMS = (size_t)N_NODES * DIM;   // 332800
    float* ws = (float*)d_ws;
    // zeroed region (contiguous): cnt[650] + als1,ald1,als2,ald2 [4*650]
    int*   cnt  = (int*)ws;
    float* als1 = ws + N_NODES;
    float* ald1 = als1 + N_NODES;
    float* als2 = ald1 + N_NODES;
    float* ald2 = als2 + N_NODES;
    // non-zeroed:
    int*   rowptr = (int*)(ald2 + N_NODES);         // 651
    int*   cursor = rowptr + N_NODES + 1;           // 650
    int*   ssrc   = cursor + N_NODES;               // 150650
    float* h1     = (float*)(ssrc + E_TOT);
    float* o1     = h1 + H_ELEMS;
    float* h2     = o1 + H_ELEMS;
    float* o2     = h2 + H_ELEMS;

    hipMemsetAsync(ws, 0, 5 * N_NODES * sizeof(float), stream);

    dim3 gG(DIM / BN, (N_NODES + BM - 1) / BM);     // 8 x 21 = 168 blocks
    int eBlocks = (E_TOT + 255) / 256;

    // ---- CSR build (topology shared by both layers) ----
    hist_kernel<<<64, 256, 0, stream>>>(ei, cnt);
    scan_kernel<<<1, 1024, 0, stream>>>(cnt, rowptr, cursor);
    scatter_kernel<<<eBlocks, 256, 0, stream>>>(ei, cursor, ssrc);

    // ---- layer 1 ----
    gemm_h<<<gG, 256, 0, stream>>>(x_s, x_t, W1, asrc1, adst1,
                                   h1, als1, ald1, N_NODES, DIM, DIM, 1);
    spmm_kernel<<<N_NODES, 256, 0, stream>>>(rowptr, ssrc, als1, ald1,
                                             h1, b1, 0.0f, o1);

    // ---- layer 2 ----
    gemm_h<<<gG, 256, 0, stream>>>(o1, nullptr, W4, asrc4, adst4,
                                   h2, als2, ald2, N_NODES, DIM, DIM, 0);
    spmm_kernel<<<N_NODES, 256, 0, stream>>>(rowptr, ssrc, als2, ald2,
                                             h2, b4, 0.01f, o2);

    // ---- final ----
    final_kernel<<<128, 256, 0, stream>>>(o2, fcw, fcb, out);
}

// Round 5
// 218.022 us; speedup vs baseline: 3.9250x; 1.4156x over previous
//
#include <hip/hip_runtime.h>
#include <math.h>

#define N_NODES 650
#define DIM     512
#define E_RAW   150000
#define E_TOT   150650

#define BM 32
#define BN 64
#define BK 32
#define KC 128            // k-chunk per split-K block
#define NZ (DIM / KC)     // 4 partials
#define CH 1024           // SpMM edge chunk (LDS)

// =============== split-K h-GEMM: P[z] = A[:, zKC:(z+1)KC] @ B[zKC:(z+1)KC, :] ===============
// a_mode 1: rows <400 from A (x_s), rows >=400 from Axt (x_t); a_mode 0: plain A[M,512]
__global__ __launch_bounds__(256)
void gemm_hp(const float* __restrict__ A, const float* __restrict__ Axt,
             const float* __restrict__ B, float* __restrict__ P,
             int M, int a_mode) {
    __shared__ float Ast[BK][BM + 2];
    __shared__ float Bs[BK][BN];
    int t  = threadIdx.x;
    int tx = t & 15, ty = t >> 4;
    int row0 = blockIdx.y * BM, col0 = blockIdx.x * BN;
    int kbase = blockIdx.z * KC;
    float acc[2][4] = {};

    for (int kb = kbase; kb < kbase + KC; kb += BK) {
        // A tile: 32x32, one float4 per thread, transposed into LDS
        {
            int m  = t >> 3;
            int kq = (t & 7) * 4;
            int gr = row0 + m, gk = kb + kq;
            float4 v = make_float4(0.f, 0.f, 0.f, 0.f);
            if (gr < M) {
                const float* rowp;
                if (a_mode == 1)
                    rowp = (gr < 400) ? (A + (size_t)gr * DIM) : (Axt + (size_t)(gr - 400) * DIM);
                else
                    rowp = A + (size_t)gr * DIM;
                v = *(const float4*)(rowp + gk);
            }
            Ast[kq + 0][m] = v.x;
            Ast[kq + 1][m] = v.y;
            Ast[kq + 2][m] = v.z;
            Ast[kq + 3][m] = v.w;
        }
        // B tile: 32x64, two float4 per thread
        {
            int n4 = (t & 15) * 4;
            #pragma unroll
            for (int p = 0; p < 2; p++) {
                int kk = (t >> 4) + p * 16;
                *(float4*)&Bs[kk][n4] = *(const float4*)&B[(size_t)(kb + kk) * DIM + col0 + n4];
            }
        }
        __syncthreads();
        #pragma unroll
        for (int kk = 0; kk < BK; kk++) {
            float2 a2 = *(const float2*)&Ast[kk][ty * 2];
            float4 b4 = *(const float4*)&Bs[kk][tx * 4];
            acc[0][0] += a2.x * b4.x; acc[0][1] += a2.x * b4.y;
            acc[0][2] += a2.x * b4.z; acc[0][3] += a2.x * b4.w;
            acc[1][0] += a2.y * b4.x; acc[1][1] += a2.y * b4.y;
            acc[1][2] += a2.y * b4.z; acc[1][3] += a2.y * b4.w;
        }
        __syncthreads();
    }

    float* Cout = P + (size_t)blockIdx.z * N_NODES * DIM;
    int gc0 = col0 + tx * 4;
    #pragma unroll
    for (int i = 0; i < 2; i++) {
        int gr = row0 + ty * 2 + i;
        if (gr < M)
            *(float4*)&Cout[(size_t)gr * DIM + gc0] =
                make_float4(acc[i][0], acc[i][1], acc[i][2], acc[i][3]);
    }
}

// =============== reduce partials + per-row logits ===============
// h[r] = sum_z P[z][r];  als[r] = h[r].asrc;  ald[r] = h[r].adst
__global__ __launch_bounds__(256)
void reduce_logits(const float* __restrict__ P,
                   const float* __restrict__ asrc, const float* __restrict__ adst,
                   float* __restrict__ h, float* __restrict__ als, float* __restrict__ ald) {
    __shared__ float red[8];
    const size_t S = (size_t)N_NODES * DIM;
    int r = blockIdx.x, t = threadIdx.x;
    size_t base = (size_t)r * DIM;
    float v0 = 0.f, v1 = 0.f;
    #pragma unroll
    for (int z = 0; z < NZ; z++) {
        v0 += P[z * S + base + t];
        v1 += P[z * S + base + t + 256];
    }
    h[base + t]       = v0;
    h[base + t + 256] = v1;
    float ps = v0 * asrc[t] + v1 * asrc[t + 256];
    float pd = v0 * adst[t] + v1 * adst[t + 256];
    #pragma unroll
    for (int o = 32; o > 0; o >>= 1) {
        ps += __shfl_down(ps, o);
        pd += __shfl_down(pd, o);
    }
    if ((t & 63) == 0) { red[t >> 6] = ps; red[4 + (t >> 6)] = pd; }
    __syncthreads();
    if (t == 0) als[r] = red[0] + red[1] + red[2] + red[3];
    if (t == 1) ald[r] = red[4] + red[5] + red[6] + red[7];
}

// =============== CSR build ===============
__global__ __launch_bounds__(256)
void hist_kernel(const int* __restrict__ ei, int* __restrict__ cnt) {
    __shared__ int h[N_NODES];
    for (int l = threadIdx.x; l < N_NODES; l += 256) h[l] = 0;
    __syncthreads();
    for (int i = blockIdx.x * 256 + threadIdx.x; i < E_TOT; i += gridDim.x * 256) {
        int d = (i < E_RAW) ? ei[E_RAW + i] : i - E_RAW;
        atomicAdd(&h[d], 1);
    }
    __syncthreads();
    for (int l = threadIdx.x; l < N_NODES; l += 256) {
        int v = h[l];
        if (v) atomicAdd(&cnt[l], v);
    }
}

__global__ __launch_bounds__(1024)
void scan_kernel(const int* __restrict__ cnt, int* __restrict__ rowptr,
                 int* __restrict__ cursor) {
    __shared__ int buf[1024];
    int t = threadIdx.x;
    buf[t] = (t < N_NODES) ? cnt[t] : 0;
    __syncthreads();
    #pragma unroll
    for (int o = 1; o < 1024; o <<= 1) {
        int v = (t >= o) ? buf[t - o] : 0;
        __syncthreads();
        buf[t] += v;
        __syncthreads();
    }
    if (t < N_NODES) {
        int excl = (t == 0) ? 0 : buf[t - 1];
        rowptr[t] = excl;
        cursor[t] = excl;
    }
    if (t == 0) rowptr[N_NODES] = buf[N_NODES - 1];
}

__global__ __launch_bounds__(256)
void scatter_kernel(const int* __restrict__ ei, int* __restrict__ cursor,
                    int* __restrict__ ssrc) {
    int i = blockIdx.x * 256 + threadIdx.x;
    if (i >= E_TOT) return;
    int s, d;
    if (i < E_RAW) { s = ei[i]; d = ei[E_RAW + i]; }
    else           { s = d = i - E_RAW; }
    int pos = atomicAdd(&cursor[d], 1);
    ssrc[pos] = s;
}

// =============== SpMM: out[d,c] = act( (Σ_e ex_e·h[src_e,c]) / Σ ex + bias[c] ) ===============
// grid (650, 2); thread owns dim c = by*256 + t.
__global__ __launch_bounds__(256)
void spmm_kernel(const int* __restrict__ rowptr, const int* __restrict__ ssrc,
                 const float* __restrict__ als, const float* __restrict__ ald,
                 const float* __restrict__ h, const float* __restrict__ bias,
                 float slope, float* __restrict__ outm) {
    __shared__ int   sS[CH];
    __shared__ float sE[CH];
    __shared__ float red[4];
    int d = blockIdx.x;
    int t = threadIdx.x;
    int c = blockIdx.y * 256 + t;
    int r0 = rowptr[d], r1 = rowptr[d + 1];
    int deg = r1 - r0;
    float aldd = ald[d];
    float acc = 0.f, psum = 0.f;

    for (int cb = 0; cb < deg; cb += CH) {
        int n = min(CH, deg - cb);
        __syncthreads();
        for (int l = t; l < n; l += 256) {
            int s = ssrc[r0 + cb + l];
            float v = als[s] + aldd;
            v = v > 0.f ? v : 0.2f * v;
            float ex = __expf(v);
            sS[l] = s;
            sE[l] = ex;
            psum += ex;
        }
        __syncthreads();
        int e = 0;
        for (; e + 4 <= n; e += 4) {
            int   s0 = sS[e],   s1 = sS[e+1], s2 = sS[e+2], s3 = sS[e+3];
            float e0 = sE[e],   e1 = sE[e+1], e2 = sE[e+2], e3 = sE[e+3];
            float x0 = h[(size_t)s0 * DIM + c];
            float x1 = h[(size_t)s1 * DIM + c];
            float x2 = h[(size_t)s2 * DIM + c];
            float x3 = h[(size_t)s3 * DIM + c];
            acc += e0 * x0 + e1 * x1 + e2 * x2 + e3 * x3;
        }
        for (; e < n; e++)
            acc += sE[e] * h[(size_t)sS[e] * DIM + c];
    }

    #pragma unroll
    for (int o = 32; o > 0; o >>= 1) psum += __shfl_down(psum, o);
    if ((t & 63) == 0) red[t >> 6] = psum;
    __syncthreads();
    float sum = red[0] + red[1] + red[2] + red[3];
    float v = acc / (sum + 1e-16f) + bias[c];
    v = v > 0.f ? v : slope * v;
    outm[(size_t)d * DIM + c] = v;
}

// =============== final: reshape(512,650) @ fc_w + fc_b -> sigmoid ===============
__global__ void final_kernel(const float* __restrict__ o2,
                             const float* __restrict__ fcw,
                             const float* __restrict__ fcb,
                             float* __restrict__ out) {
    int b = blockIdx.x * 4 + (threadIdx.x >> 6);
    int lane = threadIdx.x & 63;
    if (b >= 512) return;
    float s = 0.f;
    for (int i = lane; i < N_NODES; i += 64)
        s += o2[b * N_NODES + i] * fcw[i];
    #pragma unroll
    for (int o = 32; o > 0; o >>= 1) s += __shfl_down(s, o);
    if (lane == 0) out[b] = 1.f / (1.f + expf(-(s + fcb[0])));
}

extern "C" void kernel_launch(void* const* d_in, const int* in_sizes, int n_in,
                              void* d_out, int out_size, void* d_ws, size_t ws_size,
                              hipStream_t stream) {
    const float* x_s   = (const float*)d_in[0];
    const float* x_t   = (const float*)d_in[1];
    const int*   ei    = (const int*)d_in[2];
    const float* W1    = (const float*)d_in[5];
    const float* asrc1 = (const float*)d_in[6];
    const float* adst1 = (const float*)d_in[7];
    const float* b1    = (const float*)d_in[8];
    const float* W4    = (const float*)d_in[9];
    const float* asrc4 = (const float*)d_in[10];
    const float* adst4 = (const float*)d_in[11];
    const float* b4    = (const float*)d_in[12];
    const float* fcw   = (const float*)d_in[13];
    const float* fcb   = (const float*)d_in[14];
    float* out = (float*)d_out;

    const size_t H_ELEMS = (size_t)N_NODES * DIM;   // 332800
    float* ws = (float*)d_ws;
    // zeroed: cnt[650]
    int*   cnt    = (int*)ws;
    int*   rowptr = cnt + N_NODES;                  // 651
    int*   cursor = rowptr + N_NODES + 1;           // 650
    int*   ssrc   = cursor + N_NODES;               // 150650
    float* als1   = (float*)(ssrc + E_TOT);
    float* ald1   = als1 + N_NODES;
    float* als2   = ald1 + N_NODES;
    float* ald2   = als2 + N_NODES;
    float* P      = ald2 + N_NODES;                 // NZ * H_ELEMS (reused both layers)
    float* h1     = P + (size_t)NZ * H_ELEMS;       // aliased for h2
    float* o1     = h1 + H_ELEMS;                   // aliased for o2
    float* h2     = h1;
    float* o2     = o1;

    hipMemsetAsync(cnt, 0, N_NODES * sizeof(int), stream);

    dim3 gG(DIM / BN, (N_NODES + BM - 1) / BM, NZ); // 8 x 21 x 4 = 672 blocks
    dim3 gS(N_NODES, 2);                            // 1300 blocks
    int eBlocks = (E_TOT + 255) / 256;

    // ---- CSR build (topology shared by both layers) ----
    hist_kernel<<<64, 256, 0, stream>>>(ei, cnt);
    scan_kernel<<<1, 1024, 0, stream>>>(cnt, rowptr, cursor);
    scatter_kernel<<<eBlocks, 256, 0, stream>>>(ei, cursor, ssrc);

    // ---- layer 1 ----
    gemm_hp<<<gG, 256, 0, stream>>>(x_s, x_t, W1, P, N_NODES, 1);
    reduce_logits<<<N_NODES, 256, 0, stream>>>(P, asrc1, adst1, h1, als1, ald1);
    spmm_kernel<<<gS, 256, 0, stream>>>(rowptr, ssrc, als1, ald1, h1, b1, 0.0f, o1);

    // ---- layer 2 ----
    gemm_hp<<<gG, 256, 0, stream>>>(o1, nullptr, W4, P, N_NODES, 0);
    reduce_logits<<<N_NODES, 256, 0, stream>>>(P, asrc4, adst4, h2, als2, ald2);
    spmm_kernel<<<gS, 256, 0, stream>>>(rowptr, ssrc, als2, ald2, h2, b4, 0.01f, o2);

    // ---- final ----
    final_kernel<<<128, 256, 0, stream>>>(o2, fcw, fcb, out);
}

// Round 6
// 189.102 us; speedup vs baseline: 4.5252x; 1.1529x over previous
//
#include <hip/hip_runtime.h>
#include <math.h>

#define N_NODES 650
#define DIM     512
#define E_RAW   150000
#define E_TOT   150650

#define BM 16
#define BN 64
#define BK 32
#define KC 128            // k-chunk per split-K block
#define NZ (DIM / KC)     // 4 partials
#define CH 1024           // SpMM edge chunk (LDS)
#define NB 64             // binning blocks for CSR build

// =============== split-K h-GEMM: P[z] = A[:, zKC:(z+1)KC] @ B[zKC:(z+1)KC, :] ===============
// a_mode 1: rows <400 from A (x_s), rows >=400 from Axt (x_t); a_mode 0: plain A[M,512]
__global__ __launch_bounds__(256)
void gemm_hp(const float* __restrict__ A, const float* __restrict__ Axt,
             const float* __restrict__ B, float* __restrict__ P,
             int M, int a_mode) {
    __shared__ float Ast[BK][BM + 2];   // 32 x 18
    __shared__ float Bs[BK][BN];
    int t  = threadIdx.x;
    int tx = t & 15, ty = t >> 4;       // ty 0..15 = output row
    int row0 = blockIdx.y * BM, col0 = blockIdx.x * BN;
    int kbase = blockIdx.z * KC;
    float acc[4] = {};

    for (int kb = kbase; kb < kbase + KC; kb += BK) {
        // A tile: 16x32, threads 0..127 load one float4, transposed into LDS
        if (t < 128) {
            int m  = t >> 3;            // 0..15
            int kq = (t & 7) * 4;       // 0..28
            int gr = row0 + m;
            float4 v = make_float4(0.f, 0.f, 0.f, 0.f);
            if (gr < M) {
                const float* rowp;
                if (a_mode == 1)
                    rowp = (gr < 400) ? (A + (size_t)gr * DIM) : (Axt + (size_t)(gr - 400) * DIM);
                else
                    rowp = A + (size_t)gr * DIM;
                v = *(const float4*)(rowp + kb + kq);
            }
            Ast[kq + 0][m] = v.x;
            Ast[kq + 1][m] = v.y;
            Ast[kq + 2][m] = v.z;
            Ast[kq + 3][m] = v.w;
        }
        // B tile: 32x64, two float4 per thread
        {
            int n4 = (t & 15) * 4;
            int kk = t >> 4;
            #pragma unroll
            for (int p = 0; p < 2; p++)
                *(float4*)&Bs[kk + p * 16][n4] =
                    *(const float4*)&B[(size_t)(kb + kk + p * 16) * DIM + col0 + n4];
        }
        __syncthreads();
        #pragma unroll
        for (int kk = 0; kk < BK; kk++) {
            float a = Ast[kk][ty];
            float4 b4 = *(const float4*)&Bs[kk][tx * 4];
            acc[0] += a * b4.x; acc[1] += a * b4.y;
            acc[2] += a * b4.z; acc[3] += a * b4.w;
        }
        __syncthreads();
    }

    float* Cout = P + (size_t)blockIdx.z * N_NODES * DIM;
    int gr = row0 + ty;
    if (gr < M)
        *(float4*)&Cout[(size_t)gr * DIM + col0 + tx * 4] =
            make_float4(acc[0], acc[1], acc[2], acc[3]);
}

// =============== reduce partials + per-row logits ===============
__global__ __launch_bounds__(256)
void reduce_logits(const float* __restrict__ P,
                   const float* __restrict__ asrc, const float* __restrict__ adst,
                   float* __restrict__ h, float* __restrict__ als, float* __restrict__ ald) {
    __shared__ float red[8];
    const size_t S = (size_t)N_NODES * DIM;
    int r = blockIdx.x, t = threadIdx.x;
    size_t base = (size_t)r * DIM;
    float v0 = 0.f, v1 = 0.f;
    #pragma unroll
    for (int z = 0; z < NZ; z++) {
        v0 += P[z * S + base + t];
        v1 += P[z * S + base + t + 256];
    }
    h[base + t]       = v0;
    h[base + t + 256] = v1;
    float ps = v0 * asrc[t] + v1 * asrc[t + 256];
    float pd = v0 * adst[t] + v1 * adst[t + 256];
    #pragma unroll
    for (int o = 32; o > 0; o >>= 1) {
        ps += __shfl_down(ps, o);
        pd += __shfl_down(pd, o);
    }
    if ((t & 63) == 0) { red[t >> 6] = ps; red[4 + (t >> 6)] = pd; }
    __syncthreads();
    if (t == 0) als[r] = red[0] + red[1] + red[2] + red[3];
    if (t == 1) ald[r] = red[4] + red[5] + red[6] + red[7];
}

// =============== CSR build, atomic-free (binned counting sort) ===============
// pass 1: per-block LDS histogram -> cntb[b][d] (plain stores)
__global__ __launch_bounds__(256)
void count_kernel(const int* __restrict__ ei, int* __restrict__ cntb) {
    __shared__ int h[N_NODES];
    for (int l = threadIdx.x; l < N_NODES; l += 256) h[l] = 0;
    __syncthreads();
    int per = (E_TOT + NB - 1) / NB;
    int e0 = blockIdx.x * per;
    int e1 = min(e0 + per, E_TOT);
    for (int i = e0 + threadIdx.x; i < e1; i += 256) {
        int d = (i < E_RAW) ? ei[E_RAW + i] : i - E_RAW;
        atomicAdd(&h[d], 1);               // LDS only
    }
    __syncthreads();
    for (int l = threadIdx.x; l < N_NODES; l += 256)
        cntb[blockIdx.x * N_NODES + l] = h[l];
}

// pass 2: totals -> exclusive prefix -> rowptr; per-block bases baseb[b][d]
__global__ __launch_bounds__(1024)
void scanbase_kernel(const int* __restrict__ cntb, int* __restrict__ rowptr,
                     int* __restrict__ baseb) {
    __shared__ int buf[1024];
    int t = threadIdx.x;
    int tot = 0;
    if (t < N_NODES)
        for (int b = 0; b < NB; b++) tot += cntb[b * N_NODES + t];
    buf[t] = (t < N_NODES) ? tot : 0;
    __syncthreads();
    #pragma unroll
    for (int o = 1; o < 1024; o <<= 1) {
        int v = (t >= o) ? buf[t - o] : 0;
        __syncthreads();
        buf[t] += v;
        __syncthreads();
    }
    if (t < N_NODES) {
        int run = buf[t] - tot;            // exclusive prefix
        rowptr[t] = run;
        for (int b = 0; b < NB; b++) {
            baseb[b * N_NODES + t] = run;
            run += cntb[b * N_NODES + t];
        }
    }
    if (t == 0) rowptr[N_NODES] = E_TOT;
}

// pass 3: scatter with LDS-only cursors, plain global stores in contiguous runs
__global__ __launch_bounds__(256)
void scatter2_kernel(const int* __restrict__ ei, const int* __restrict__ baseb,
                     int* __restrict__ ssrc) {
    __shared__ int lcur[N_NODES];
    for (int l = threadIdx.x; l < N_NODES; l += 256)
        lcur[l] = baseb[blockIdx.x * N_NODES + l];
    __syncthreads();
    int per = (E_TOT + NB - 1) / NB;
    int e0 = blockIdx.x * per;
    int e1 = min(e0 + per, E_TOT);
    for (int i = e0 + threadIdx.x; i < e1; i += 256) {
        int s, d;
        if (i < E_RAW) { s = ei[i]; d = ei[E_RAW + i]; }
        else           { s = d = i - E_RAW; }
        int pos = atomicAdd(&lcur[d], 1);  // LDS only
        ssrc[pos] = s;
    }
}

// =============== SpMM: out[d,c] = act( (Σ_e ex_e·h[src_e,c]) / Σ ex + bias[c] ) ===============
__global__ __launch_bounds__(256)
void spmm_kernel(const int* __restrict__ rowptr, const int* __restrict__ ssrc,
                 const float* __restrict__ als, const float* __restrict__ ald,
                 const float* __restrict__ h, const float* __restrict__ bias,
                 float slope, float* __restrict__ outm) {
    __shared__ int   sS[CH];
    __shared__ float sE[CH];
    __shared__ float red[4];
    int d = blockIdx.x;
    int t = threadIdx.x;
    int c = blockIdx.y * 256 + t;
    int r0 = rowptr[d], r1 = rowptr[d + 1];
    int deg = r1 - r0;
    float aldd = ald[d];
    float acc = 0.f, psum = 0.f;

    for (int cb = 0; cb < deg; cb += CH) {
        int n = min(CH, deg - cb);
        __syncthreads();
        for (int l = t; l < n; l += 256) {
            int s = ssrc[r0 + cb + l];
            float v = als[s] + aldd;
            v = v > 0.f ? v : 0.2f * v;
            float ex = __expf(v);
            sS[l] = s;
            sE[l] = ex;
            psum += ex;
        }
        __syncthreads();
        int e = 0;
        for (; e + 4 <= n; e += 4) {
            int   s0 = sS[e],   s1 = sS[e+1], s2 = sS[e+2], s3 = sS[e+3];
            float e0 = sE[e],   e1 = sE[e+1], e2 = sE[e+2], e3 = sE[e+3];
            float x0 = h[(size_t)s0 * DIM + c];
            float x1 = h[(size_t)s1 * DIM + c];
            float x2 = h[(size_t)s2 * DIM + c];
            float x3 = h[(size_t)s3 * DIM + c];
            acc += e0 * x0 + e1 * x1 + e2 * x2 + e3 * x3;
        }
        for (; e < n; e++)
            acc += sE[e] * h[(size_t)sS[e] * DIM + c];
    }

    #pragma unroll
    for (int o = 32; o > 0; o >>= 1) psum += __shfl_down(psum, o);
    if ((t & 63) == 0) red[t >> 6] = psum;
    __syncthreads();
    float sum = red[0] + red[1] + red[2] + red[3];
    float v = acc / (sum + 1e-16f) + bias[c];
    v = v > 0.f ? v : slope * v;
    outm[(size_t)d * DIM + c] = v;
}

// =============== final: reshape(512,650) @ fc_w + fc_b -> sigmoid ===============
__global__ void final_kernel(const float* __restrict__ o2,
                             const float* __restrict__ fcw,
                             const float* __restrict__ fcb,
                             float* __restrict__ out) {
    int b = blockIdx.x * 4 + (threadIdx.x >> 6);
    int lane = threadIdx.x & 63;
    if (b >= 512) return;
    float s = 0.f;
    for (int i = lane; i < N_NODES; i += 64)
        s += o2[b * N_NODES + i] * fcw[i];
    #pragma unroll
    for (int o = 32; o > 0; o >>= 1) s += __shfl_down(s, o);
    if (lane == 0) out[b] = 1.f / (1.f + expf(-(s + fcb[0])));
}

extern "C" void kernel_launch(void* const* d_in, const int* in_sizes, int n_in,
                              void* d_out, int out_size, void* d_ws, size_t ws_size,
                              hipStream_t stream) {
    const float* x_s   = (const float*)d_in[0];
    const float* x_t   = (const float*)d_in[1];
    const int*   ei    = (const int*)d_in[2];
    const float* W1    = (const float*)d_in[5];
    const float* asrc1 = (const float*)d_in[6];
    const float* adst1 = (const float*)d_in[7];
    const float* b1    = (const float*)d_in[8];
    const float* W4    = (const float*)d_in[9];
    const float* asrc4 = (const float*)d_in[10];
    const float* adst4 = (const float*)d_in[11];
    const float* b4    = (const float*)d_in[12];
    const float* fcw   = (const float*)d_in[13];
    const float* fcb   = (const float*)d_in[14];
    float* out = (float*)d_out;

    const size_t H_ELEMS = (size_t)N_NODES * DIM;   // 332800
    float* ws = (float*)d_ws;
    int*   cntb   = (int*)ws;                       // NB*650
    int*   baseb  = cntb + NB * N_NODES;            // NB*650
    int*   rowptr = baseb + NB * N_NODES;           // 651
    int*   ssrc   = rowptr + N_NODES + 1;           // 150650
    float* als1   = (float*)(ssrc + E_TOT);
    float* ald1   = als1 + N_NODES;
    float* als2   = ald1 + N_NODES;
    float* ald2   = als2 + N_NODES;
    float* P      = ald2 + N_NODES;                 // NZ * H_ELEMS (reused both layers)
    float* h1     = P + (size_t)NZ * H_ELEMS;
    float* o1     = h1 + H_ELEMS;
    float* h2     = h1;                              // aliased
    float* o2     = o1;

    dim3 gG(DIM / BN, (N_NODES + BM - 1) / BM, NZ); // 8 x 41 x 4 = 1312 blocks
    dim3 gS(N_NODES, 2);                            // 1300 blocks

    // ---- CSR build (topology shared by both layers; zero global atomics) ----
    count_kernel<<<NB, 256, 0, stream>>>(ei, cntb);
    scanbase_kernel<<<1, 1024, 0, stream>>>(cntb, rowptr, baseb);
    scatter2_kernel<<<NB, 256, 0, stream>>>(ei, baseb, ssrc);

    // ---- layer 1 ----
    gemm_hp<<<gG, 256, 0, stream>>>(x_s, x_t, W1, P, N_NODES, 1);
    reduce_logits<<<N_NODES, 256, 0, stream>>>(P, asrc1, adst1, h1, als1, ald1);
    spmm_kernel<<<gS, 256, 0, stream>>>(rowptr, ssrc, als1, ald1, h1, b1, 0.0f, o1);

    // ---- layer 2 ----
    gemm_hp<<<gG, 256, 0, stream>>>(o1, nullptr, W4, P, N_NODES, 0);
    reduce_logits<<<N_NODES, 256, 0, stream>>>(P, asrc4, adst4, h2, als2, ald2);
    spmm_kernel<<<gS, 256, 0, stream>>>(rowptr, ssrc, als2, ald2, h2, b4, 0.01f, o2);

    // ---- final ----
    final_kernel<<<128, 256, 0, stream>>>(o2, fcw, fcb, out);
}